// Round 9
// baseline (655.893 us; speedup 1.0000x reference)
//
#include <hip/hip_runtime.h>
#include <hip/hip_bf16.h>
#include <hip/hip_fp16.h>
#include <math.h>

// Shapes: x [128,20000,1] f32; rows/cols [640000] i32; vals [640000] f32
// W_gc [20,10]; b_gc [10]; W_fc [200000,10]; b_fc [10]; out [128,10] f32.
//
// R22 = R21 + column-blocked CSR (NCB=4) for WITHIN-dispatch L2 reuse.
//  - csr sorted by key (col_block * N + row); spmm accumulates each row
//    over cb=0..3 in the same registers (no partials, no extra dispatch,
//    no extra traffic). All blocks sweep cb in order -> each XCD's L2
//    holds one 1.28MB col-slice; first touch from LLC (5.12MB/chunk/step),
//    the other ~31 touches of each line hit local L2.
//  - Unlike R19/R20 this does NOT rely on cross-dispatch L2 persistence
//    (which was falsified); reuse is captured inside one dispatch.
//  - Theory: LLC-side/step 164MB -> ~60MB => spmm 25 -> ~11-15us/step.
//    Pre-commit: spmm >= 22us/step => lever dead, declare roofline at R21.
//  - proj_fc / parallel scan / transpose: R21 verbatim (561.9us base).

#define NF 10
#define KCHEB 20
#define BCG 64                        // batch elems per chunk
#define COFF16 (KCHEB * BCG)          // 1280 fp16 elems per node in X16
#define NCB 4                         // column blocks (L2 slice = 1.28MB)

typedef unsigned int u32;

// ---------------- CSR build + small prep ----------------

__global__ void init_kernel(int* counts, float* h_part, const float* __restrict__ W_gc,
                            float* __restrict__ WgT, int NV, int H) {
    int i = blockIdx.x * blockDim.x + threadIdx.x;
    if (i < NV) counts[i] = 0;
    if (i < H) h_part[i] = 0.f;
    if (i < KCHEB * NF) WgT[(i % NF) * KCHEB + (i / NF)] = W_gc[i];  // [j][k]
}

__global__ void hist_kernel(const int* __restrict__ rows, const int* __restrict__ cols,
                            int* __restrict__ counts, int E, int N, int QS) {
    int e = blockIdx.x * blockDim.x + threadIdx.x;
    if (e < E) {
        int cb = cols[e] / QS;
        atomicAdd(&counts[cb * N + rows[e]], 1);
    }
}

// ---- 3-phase scan over NV = NCB*N virtual rows
#define SB 1024
__global__ void scan1_kernel(const int* __restrict__ counts, int* __restrict__ ex,
                             int* __restrict__ bsum, int NV) {
    __shared__ int sh[SB];
    int t = threadIdx.x;
    int i = blockIdx.x * SB + t;
    int v = (i < NV) ? counts[i] : 0;
    sh[t] = v;
    __syncthreads();
    for (int off = 1; off < SB; off <<= 1) {
        int u = (t >= off) ? sh[t - off] : 0;
        __syncthreads();
        sh[t] += u;
        __syncthreads();
    }
    if (i < NV) ex[i] = sh[t] - v;
    if (t == SB - 1) bsum[blockIdx.x] = sh[t];
}

__global__ void scan2_kernel(const int* __restrict__ bsum, int* __restrict__ boff, int nb) {
    if (threadIdx.x == 0) {
        int run = 0;
        for (int i = 0; i < nb; ++i) { boff[i] = run; run += bsum[i]; }
        boff[nb] = run;
    }
}

__global__ void scan3_kernel(int* __restrict__ row_start, int* __restrict__ cursor,
                             const int* __restrict__ ex, const int* __restrict__ boff,
                             int NV, int nb) {
    int i = blockIdx.x * blockDim.x + threadIdx.x;
    if (i < NV) {
        int v = ex[i] + boff[i >> 10];
        row_start[i] = v;
        cursor[i] = v;
    }
    if (i == NV) row_start[NV] = boff[nb];
}

// csr[p] = (col*COFF16 [element offset of node's X16 row], bits(val))
__global__ void scatter_kernel(const int* __restrict__ rows, const int* __restrict__ cols,
                               const float* __restrict__ vals, int* __restrict__ cursor,
                               int2* __restrict__ csr, int E, int N, int QS) {
    int e = blockIdx.x * blockDim.x + threadIdx.x;
    if (e >= E) return;
    int col = cols[e];
    int cb = col / QS;
    int p = atomicAdd(&cursor[cb * N + rows[e]], 1);
    csr[p] = make_int2(col * COFF16, __float_as_int(vals[e]));
}

// ---------------- T0 fill (tiled transpose; fp16 plane 0 + fp32 carry 0) ----

__global__ void transpose_kernel(const float* __restrict__ x, __half* __restrict__ X16,
                                 float* __restrict__ C32, int N, int ntiles, int b0s) {
    __shared__ float tile[BCG][65];
    int tid = threadIdx.x;
    int g = blockIdx.x / ntiles;
    int ti = blockIdx.x - g * ntiles;
    int n0 = ti * 64;
#pragma unroll
    for (int p = 0; p < 16; ++p) {
        int idx = p * 256 + tid;
        int row = idx >> 6;        // batch offset 0..63
        int col = idx & 63;        // node offset 0..63
        if (n0 + col < N)
            tile[row][col] = x[(size_t)(b0s + g * BCG + row) * N + n0 + col];
    }
    __syncthreads();
#pragma unroll
    for (int p = 0; p < 16; ++p) {
        int idx = p * 256 + tid;
        int nloc = idx >> 6;       // node offset 0..63
        int bb = idx & 63;         // batch offset 0..63
        int n = n0 + nloc;
        if (n < N) {
            float v = tile[bb][nloc];
            X16[(size_t)(g * N + n) * COFF16 + bb] = __float2half_rn(v);   // plane k=0
            C32[((size_t)(g * 2 + 0) * N + n) * BCG + bb] = v;             // carry slot 0
        }
    }
}

// ---------------- SpMM step ----------------
// Block = 256 thr = 32 rows x 8 bq lanes; each lane gathers 8 fp16 (16B), so a
// row's 8 lanes consume exactly one 128B line per edge. Row accumulates over
// NCB column blocks (csr sorted by cb*N+row) -> col-slice L2 reuse.

__global__ __launch_bounds__(256)
void spmm_kernel(__half* __restrict__ X16, float* __restrict__ C32,
                 const int* __restrict__ row_start, const int2* __restrict__ csr,
                 int N, int xpcShift, int subsPerChunk,
                 int kIn, int kOut, float alpha, float beta) {
    int xcd = blockIdx.x & 7;
    int chunk = xcd >> xpcShift;
    int xpcMask = (1 << xpcShift) - 1;
    int sub = (blockIdx.x >> 3) * (1 << xpcShift) + (xcd & xpcMask);
    if (sub >= subsPerChunk) return;
    int tid = threadIdx.x;
    int ln = tid >> 3;             // row 0..31
    int bq = tid & 7;              // 8 lanes x 8 fp16 = 64 batch
    int n = sub * 32 + ln;
    if (n >= N) return;

    const __half* gin = X16 + (size_t)chunk * N * COFF16;
    int koff = kIn * BCG + bq * 8; // gather element offset within node row
    int bo = bq * 8;
    float acc[8];
#pragma unroll
    for (int q = 0; q < 8; ++q) acc[q] = 0.f;

#pragma unroll 1
    for (int cb = 0; cb < NCB; ++cb) {
        int vr = cb * N + n;
        int s = row_start[vr];
        int e = row_start[vr + 1];
        int i = s;
        for (; i + 4 <= e; i += 4) {
            int2 p0 = csr[i], p1 = csr[i + 1], p2 = csr[i + 2], p3 = csr[i + 3];
            uint4 u0 = *(const uint4*)(gin + p0.x + koff);
            uint4 u1 = *(const uint4*)(gin + p1.x + koff);
            uint4 u2 = *(const uint4*)(gin + p2.x + koff);
            uint4 u3 = *(const uint4*)(gin + p3.x + koff);
            float v0 = __int_as_float(p0.y), v1 = __int_as_float(p1.y);
            float v2 = __int_as_float(p2.y), v3 = __int_as_float(p3.y);
            {
                float2 f0 = __half22float2(*(__half2*)&u0.x), f1 = __half22float2(*(__half2*)&u0.y);
                float2 f2 = __half22float2(*(__half2*)&u0.z), f3 = __half22float2(*(__half2*)&u0.w);
                acc[0] += v0 * f0.x; acc[1] += v0 * f0.y; acc[2] += v0 * f1.x; acc[3] += v0 * f1.y;
                acc[4] += v0 * f2.x; acc[5] += v0 * f2.y; acc[6] += v0 * f3.x; acc[7] += v0 * f3.y;
            }
            {
                float2 f0 = __half22float2(*(__half2*)&u1.x), f1 = __half22float2(*(__half2*)&u1.y);
                float2 f2 = __half22float2(*(__half2*)&u1.z), f3 = __half22float2(*(__half2*)&u1.w);
                acc[0] += v1 * f0.x; acc[1] += v1 * f0.y; acc[2] += v1 * f1.x; acc[3] += v1 * f1.y;
                acc[4] += v1 * f2.x; acc[5] += v1 * f2.y; acc[6] += v1 * f3.x; acc[7] += v1 * f3.y;
            }
            {
                float2 f0 = __half22float2(*(__half2*)&u2.x), f1 = __half22float2(*(__half2*)&u2.y);
                float2 f2 = __half22float2(*(__half2*)&u2.z), f3 = __half22float2(*(__half2*)&u2.w);
                acc[0] += v2 * f0.x; acc[1] += v2 * f0.y; acc[2] += v2 * f1.x; acc[3] += v2 * f1.y;
                acc[4] += v2 * f2.x; acc[5] += v2 * f2.y; acc[6] += v2 * f3.x; acc[7] += v2 * f3.y;
            }
            {
                float2 f0 = __half22float2(*(__half2*)&u3.x), f1 = __half22float2(*(__half2*)&u3.y);
                float2 f2 = __half22float2(*(__half2*)&u3.z), f3 = __half22float2(*(__half2*)&u3.w);
                acc[0] += v3 * f0.x; acc[1] += v3 * f0.y; acc[2] += v3 * f1.x; acc[3] += v3 * f1.y;
                acc[4] += v3 * f2.x; acc[5] += v3 * f2.y; acc[6] += v3 * f3.x; acc[7] += v3 * f3.y;
            }
        }
        for (; i < e; ++i) {
            int2 p0 = csr[i];
            uint4 u0 = *(const uint4*)(gin + p0.x + koff);
            float v0 = __int_as_float(p0.y);
            float2 f0 = __half22float2(*(__half2*)&u0.x), f1 = __half22float2(*(__half2*)&u0.y);
            float2 f2 = __half22float2(*(__half2*)&u0.z), f3 = __half22float2(*(__half2*)&u0.w);
            acc[0] += v0 * f0.x; acc[1] += v0 * f0.y; acc[2] += v0 * f1.x; acc[3] += v0 * f1.y;
            acc[4] += v0 * f2.x; acc[5] += v0 * f2.y; acc[6] += v0 * f3.x; acc[7] += v0 * f3.y;
        }
    }

    // carry slot: (k-2)&1 == k&1, so read T_{k-2} and write T_k at the SAME
    // address (thread-private location -> safe).
    float* cslot = C32 + ((size_t)(chunk * 2 + (kOut & 1)) * N + n) * BCG + bo;
    float o[8];
#pragma unroll
    for (int q = 0; q < 8; ++q) o[q] = alpha * acc[q];
    if (beta != 0.f) {
        const float4 pv0 = *(const float4*)(cslot);
        const float4 pv1 = *(const float4*)(cslot + 4);
        o[0] += beta * pv0.x; o[1] += beta * pv0.y; o[2] += beta * pv0.z; o[3] += beta * pv0.w;
        o[4] += beta * pv1.x; o[5] += beta * pv1.y; o[6] += beta * pv1.z; o[7] += beta * pv1.w;
    }
    *(float4*)(cslot)     = make_float4(o[0], o[1], o[2], o[3]);
    *(float4*)(cslot + 4) = make_float4(o[4], o[5], o[6], o[7]);
    __half* o16 = X16 + (size_t)(chunk * N + n) * COFF16 + kOut * BCG + bo;
    uint4 h4;
    __half2 h01 = __floats2half2_rn(o[0], o[1]);
    __half2 h23 = __floats2half2_rn(o[2], o[3]);
    __half2 h45 = __floats2half2_rn(o[4], o[5]);
    __half2 h67 = __floats2half2_rn(o[6], o[7]);
    h4.x = *(u32*)&h01; h4.y = *(u32*)&h23; h4.z = *(u32*)&h45; h4.w = *(u32*)&h67;
    *(uint4*)o16 = h4;
}

// ---------------- Fused projection + FC partial ----------------
// Block = 1024 thr = 16 waves; wave = one node x 64 bb lanes. All weight reads
// (WgT row, W_fc row, bias) are wave-uniform -> scalar loads on the SMEM pipe.

__global__ __launch_bounds__(1024, 8)
void proj_fc_kernel(const __half* __restrict__ X16,
                    const float* __restrict__ WgT,    // [j][k] = [10][20]
                    const float* __restrict__ b_gc,
                    const float* __restrict__ W_fc,
                    float* __restrict__ h_part,
                    int N, int b0s, int G) {
    __shared__ float sRed[BCG * 11];
    int tid = threadIdx.x;
    for (int i = tid; i < BCG * 11; i += 1024) sRed[i] = 0.f;
    __syncthreads();

    int g = blockIdx.x % G;
    int bidx = blockIdx.x / G;
    int nblk = gridDim.x / G;

    int bb = tid & (BCG - 1);
    int wv = __builtin_amdgcn_readfirstlane(tid >> 6);   // wave slot 0..15, uniform

    float h_loc[NF];
#pragma unroll
    for (int f = 0; f < NF; ++f) h_loc[f] = 0.f;

    const __half* chunkBase = X16 + (size_t)g * N * COFF16;
    int ngroups = (N + 15) / 16;
    for (int grp = bidx; grp < ngroups; grp += nblk) {
        int n = grp * 16 + wv;                           // uniform per wave
        if (n < N) {
            float xt[KCHEB];
            const __half* xp = chunkBase + (size_t)n * COFF16 + bb;
#pragma unroll
            for (int k = 0; k < KCHEB; ++k) xt[k] = __half2float(xp[k * BCG]);

            const float* wfBase = W_fc + (size_t)n * (NF * NF);
#pragma unroll 1
            for (int j = 0; j < NF; ++j) {
                const float* wg = WgT + j * KCHEB;       // 16B-aligned, contiguous 20f
                float gc = b_gc[j];
#pragma unroll
                for (int k = 0; k < KCHEB; ++k) gc += wg[k] * xt[k];
                gc = fmaxf(gc, 0.f);
                const float* wf = wfBase + j * NF;       // 8B-aligned, contiguous 10f
#pragma unroll
                for (int f = 0; f < NF; ++f) h_loc[f] += gc * wf[f];
            }
        }
    }
#pragma unroll
    for (int f = 0; f < NF; ++f) atomicAdd(&sRed[bb * 11 + f], h_loc[f]);
    __syncthreads();
    for (int i = tid; i < BCG * NF; i += 1024) {
        int rb = i / NF;
        int rf = i - rb * NF;
        atomicAdd(&h_part[(size_t)(b0s + g * BCG + rb) * NF + rf], sRed[rb * 11 + rf]);
    }
}

// ---------------- Bias + ReLU + softmax ----------------

__global__ void softmax_kernel(const float* __restrict__ h_part, const float* __restrict__ b_fc,
                               float* __restrict__ out, int B) {
    int b = blockIdx.x * blockDim.x + threadIdx.x;
    if (b >= B) return;
    float v[NF];
    float m = -1e30f;
#pragma unroll
    for (int f = 0; f < NF; ++f) {
        float t = fmaxf(h_part[b * NF + f] + b_fc[f], 0.f);
        v[f] = t;
        m = fmaxf(m, t);
    }
    float s = 0.f;
#pragma unroll
    for (int f = 0; f < NF; ++f) { v[f] = expf(v[f] - m); s += v[f]; }
    float inv = 1.f / s;
#pragma unroll
    for (int f = 0; f < NF; ++f) out[b * NF + f] = v[f] * inv;
}

// ---------------- launch ----------------

extern "C" void kernel_launch(void* const* d_in, const int* in_sizes, int n_in,
                              void* d_out, int out_size, void* d_ws, size_t ws_size,
                              hipStream_t stream) {
    const float* x    = (const float*)d_in[0];
    const int*   rows = (const int*)d_in[1];
    const int*   cols = (const int*)d_in[2];
    const float* vals = (const float*)d_in[3];
    const float* W_gc = (const float*)d_in[4];
    const float* b_gc = (const float*)d_in[5];
    const float* W_fc = (const float*)d_in[6];
    const float* b_fc = (const float*)d_in[7];
    float* out = (float*)d_out;

    const int E = in_sizes[1];
    const int N = in_sizes[6] / (NF * NF);
    const int B = in_sizes[0] / N;
    const int NV = NCB * N;
    const int QS = (N + NCB - 1) / NCB;

    // ---- workspace carve ----
    char* p = (char*)d_ws;
    int* counts    = (int*)p;   p += sizeof(int) * (size_t)NV;
    int* row_start = (int*)p;   p += sizeof(int) * (size_t)(NV + 1);
    int* cursor    = (int*)p;   p += sizeof(int) * (size_t)NV;
    int* exbuf     = (int*)p;   p += sizeof(int) * (size_t)NV;
    int* bsum      = (int*)p;   p += sizeof(int) * 160;
    int* boff      = (int*)p;   p += sizeof(int) * 160;
    p = (char*)(((size_t)p + 15) & ~(size_t)15);
    int2* csr      = (int2*)p;  p += sizeof(int2) * (size_t)E;
    float* h_part  = (float*)p; p += sizeof(float) * (size_t)B * NF;
    p = (char*)(((size_t)p + 15) & ~(size_t)15);
    float* WgT     = (float*)p; p += sizeof(float) * (size_t)(NF * KCHEB);
    size_t fixed = (size_t)(p - (char*)d_ws);
    fixed = (fixed + 255) & ~(size_t)255;

    // G chunks of BCG=64 resident (G in {2,1}); B=128 -> G=2, single pass
    size_t perChunk16 = (size_t)N * COFF16 * sizeof(__half);     // 51.2 MB
    size_t perCarry   = (size_t)2 * N * BCG * sizeof(float);     // 10.24 MB
    int G = (B >= 2 * BCG) ? 2 : 1;
    while (G > 1 && fixed + (size_t)G * (perChunk16 + perCarry) > ws_size) G >>= 1;
    __half* X16 = (__half*)((char*)d_ws + fixed);
    size_t x16b = ((size_t)G * perChunk16 + 255) & ~(size_t)255;
    float* C32 = (float*)((char*)d_ws + fixed + x16b);
    int xpcShift = (G == 2) ? 2 : 3;
    int BT = G * BCG;
    int nsc = B / BT;

    // ---- CSR build (col-blocked, parallel scan) + WgT prep ----
    {
        int H = B * NF;
        int cov = (NV > H) ? NV : H;
        int nb = (NV + SB - 1) / SB;
        init_kernel<<<(cov + 255) / 256, 256, 0, stream>>>(counts, h_part, W_gc, WgT, NV, H);
        hist_kernel<<<(E + 255) / 256, 256, 0, stream>>>(rows, cols, counts, E, N, QS);
        scan1_kernel<<<nb, SB, 0, stream>>>(counts, exbuf, bsum, NV);
        scan2_kernel<<<1, 64, 0, stream>>>(bsum, boff, nb);
        scan3_kernel<<<(NV + 256) / 256, 256, 0, stream>>>(row_start, cursor, exbuf, boff, NV, nb);
        scatter_kernel<<<(E + 255) / 256, 256, 0, stream>>>(rows, cols, vals, cursor, csr, E, N, QS);
    }

    int ntiles = (N + 63) / 64;
    int subsPerChunk = (N + 31) / 32;
    int xpc = 1 << xpcShift;
    int gridSpmm = 8 * ((subsPerChunk + xpc - 1) / xpc);

    for (int c = 0; c < nsc; ++c) {
        int b0s = c * BT;
        transpose_kernel<<<G * ntiles, 256, 0, stream>>>(x, X16, C32, N, ntiles, b0s);
        for (int k = 1; k < KCHEB; ++k) {
            float alpha = (k == 1) ? 1.f : 2.f;
            float beta  = (k == 1) ? 0.f : -1.f;
            spmm_kernel<<<gridSpmm, 256, 0, stream>>>(
                X16, C32, row_start, csr, N, xpcShift, subsPerChunk,
                k - 1, k, alpha, beta);
        }
        proj_fc_kernel<<<256 * G, 1024, 0, stream>>>(X16, WgT, b_gc, W_fc, h_part, N, b0s, G);
    }

    softmax_kernel<<<1, 128, 0, stream>>>(h_part, b_fc, out, B);
}

// Round 10
// 565.353 us; speedup vs baseline: 1.1601x; 1.1601x over previous
//
#include <hip/hip_runtime.h>
#include <hip/hip_bf16.h>
#include <hip/hip_fp16.h>
#include <math.h>

// Shapes: x [128,20000,1] f32; rows/cols [640000] i32; vals [640000] f32
// W_gc [20,10]; b_gc [10]; W_fc [200000,10]; b_fc [10]; out [128,10] f32.
//
// R23 = R21 verbatim (best verified, 561.9us). Final configuration.
//  - SpMM floor is structural: ~164MB/step of payload-minimal random
//    128B line service from LLC @ ~6.5TB/s = 25us/step x 19 steps = 475us.
//    Falsified alternatives: gather/reduce col-partition (R18b, 33us/step),
//    plane-major per-XCD chunks (R19, 65us/step), small-chunk L2-fit
//    (R20, 55us/step), within-dispatch col-blocking (R22, +5us/step).
//    BCG=64 means one edge-gather = one full 128B line (minimum traffic).
//  - proj_fc: wave-uniform scalar-weight structure, ~53us latency plateau
//    at 100% static occupancy (LDS-staged and scalar variants equal).
//  - CSR build with 3-phase parallel scan (~8us, was 50us single-block).

#define NF 10
#define KCHEB 20
#define BCG 64                        // batch elems per chunk
#define COFF16 (KCHEB * BCG)          // 1280 fp16 elems per node in X16

typedef unsigned int u32;

// ---------------- CSR build + small prep ----------------

__global__ void init_kernel(int* counts, float* h_part, const float* __restrict__ W_gc,
                            float* __restrict__ WgT, int N, int H) {
    int i = blockIdx.x * blockDim.x + threadIdx.x;
    if (i < N) counts[i] = 0;
    if (i < H) h_part[i] = 0.f;
    if (i < KCHEB * NF) WgT[(i % NF) * KCHEB + (i / NF)] = W_gc[i];  // [j][k]
}

__global__ void hist_kernel(const int* __restrict__ rows, int* __restrict__ counts, int E) {
    int e = blockIdx.x * blockDim.x + threadIdx.x;
    if (e < E) atomicAdd(&counts[rows[e]], 1);
}

// ---- 3-phase scan: ex[i] = exclusive prefix within block; bsum = block sums
#define SB 1024
__global__ void scan1_kernel(const int* __restrict__ counts, int* __restrict__ ex,
                             int* __restrict__ bsum, int N) {
    __shared__ int sh[SB];
    int t = threadIdx.x;
    int i = blockIdx.x * SB + t;
    int v = (i < N) ? counts[i] : 0;
    sh[t] = v;
    __syncthreads();
    for (int off = 1; off < SB; off <<= 1) {
        int u = (t >= off) ? sh[t - off] : 0;
        __syncthreads();
        sh[t] += u;
        __syncthreads();
    }
    if (i < N) ex[i] = sh[t] - v;
    if (t == SB - 1) bsum[blockIdx.x] = sh[t];
}

__global__ void scan2_kernel(const int* __restrict__ bsum, int* __restrict__ boff, int nb) {
    if (threadIdx.x == 0) {
        int run = 0;
        for (int i = 0; i < nb; ++i) { boff[i] = run; run += bsum[i]; }
        boff[nb] = run;
    }
}

__global__ void scan3_kernel(int* __restrict__ row_start, int* __restrict__ cursor,
                             const int* __restrict__ ex, const int* __restrict__ boff,
                             int N, int nb) {
    int i = blockIdx.x * blockDim.x + threadIdx.x;
    if (i < N) {
        int v = ex[i] + boff[i >> 10];
        row_start[i] = v;
        cursor[i] = v;
    }
    if (i == N) row_start[N] = boff[nb];
}

// csr[p] = (col*COFF16 [element offset of node's X16 row], bits(val))
__global__ void scatter_kernel(const int* __restrict__ rows, const int* __restrict__ cols,
                               const float* __restrict__ vals, int* __restrict__ cursor,
                               int2* __restrict__ csr, int E) {
    int e = blockIdx.x * blockDim.x + threadIdx.x;
    if (e >= E) return;
    int p = atomicAdd(&cursor[rows[e]], 1);
    csr[p] = make_int2(cols[e] * COFF16, __float_as_int(vals[e]));
}

// ---------------- T0 fill (tiled transpose; fp16 plane 0 + fp32 carry 0) ----

__global__ void transpose_kernel(const float* __restrict__ x, __half* __restrict__ X16,
                                 float* __restrict__ C32, int N, int ntiles, int b0s) {
    __shared__ float tile[BCG][65];
    int tid = threadIdx.x;
    int g = blockIdx.x / ntiles;
    int ti = blockIdx.x - g * ntiles;
    int n0 = ti * 64;
#pragma unroll
    for (int p = 0; p < 16; ++p) {
        int idx = p * 256 + tid;
        int row = idx >> 6;        // batch offset 0..63
        int col = idx & 63;        // node offset 0..63
        if (n0 + col < N)
            tile[row][col] = x[(size_t)(b0s + g * BCG + row) * N + n0 + col];
    }
    __syncthreads();
#pragma unroll
    for (int p = 0; p < 16; ++p) {
        int idx = p * 256 + tid;
        int nloc = idx >> 6;       // node offset 0..63
        int bb = idx & 63;         // batch offset 0..63
        int n = n0 + nloc;
        if (n < N) {
            float v = tile[bb][nloc];
            X16[(size_t)(g * N + n) * COFF16 + bb] = __float2half_rn(v);   // plane k=0
            C32[((size_t)(g * 2 + 0) * N + n) * BCG + bb] = v;             // carry slot 0
        }
    }
}

// ---------------- SpMM step ----------------
// Block = 256 thr = 32 rows x 8 bq lanes; each lane gathers 8 fp16 (16B), so a
// row's 8 lanes consume exactly one 128B line per edge.
// Carry math fp32 via C32 rotating slots; outputs: C32[k&1] + X16 plane k.

__global__ __launch_bounds__(256)
void spmm_kernel(__half* __restrict__ X16, float* __restrict__ C32,
                 const int* __restrict__ row_start, const int2* __restrict__ csr,
                 int N, int xpcShift, int subsPerChunk,
                 int kIn, int kOut, float alpha, float beta) {
    int xcd = blockIdx.x & 7;
    int chunk = xcd >> xpcShift;
    int xpcMask = (1 << xpcShift) - 1;
    int sub = (blockIdx.x >> 3) * (1 << xpcShift) + (xcd & xpcMask);
    if (sub >= subsPerChunk) return;
    int tid = threadIdx.x;
    int ln = tid >> 3;             // row 0..31
    int bq = tid & 7;              // 8 lanes x 8 fp16 = 64 batch
    int n = sub * 32 + ln;
    if (n >= N) return;
    int s = row_start[n];
    int e = row_start[n + 1];

    const __half* gin = X16 + (size_t)chunk * N * COFF16;
    int koff = kIn * BCG + bq * 8; // gather element offset within node row
    int bo = bq * 8;
    float acc[8];
#pragma unroll
    for (int q = 0; q < 8; ++q) acc[q] = 0.f;

    int i = s;
    for (; i + 4 <= e; i += 4) {
        int2 p0 = csr[i], p1 = csr[i + 1], p2 = csr[i + 2], p3 = csr[i + 3];
        uint4 u0 = *(const uint4*)(gin + p0.x + koff);
        uint4 u1 = *(const uint4*)(gin + p1.x + koff);
        uint4 u2 = *(const uint4*)(gin + p2.x + koff);
        uint4 u3 = *(const uint4*)(gin + p3.x + koff);
        float v0 = __int_as_float(p0.y), v1 = __int_as_float(p1.y);
        float v2 = __int_as_float(p2.y), v3 = __int_as_float(p3.y);
        {
            float2 f0 = __half22float2(*(__half2*)&u0.x), f1 = __half22float2(*(__half2*)&u0.y);
            float2 f2 = __half22float2(*(__half2*)&u0.z), f3 = __half22float2(*(__half2*)&u0.w);
            acc[0] += v0 * f0.x; acc[1] += v0 * f0.y; acc[2] += v0 * f1.x; acc[3] += v0 * f1.y;
            acc[4] += v0 * f2.x; acc[5] += v0 * f2.y; acc[6] += v0 * f3.x; acc[7] += v0 * f3.y;
        }
        {
            float2 f0 = __half22float2(*(__half2*)&u1.x), f1 = __half22float2(*(__half2*)&u1.y);
            float2 f2 = __half22float2(*(__half2*)&u1.z), f3 = __half22float2(*(__half2*)&u1.w);
            acc[0] += v1 * f0.x; acc[1] += v1 * f0.y; acc[2] += v1 * f1.x; acc[3] += v1 * f1.y;
            acc[4] += v1 * f2.x; acc[5] += v1 * f2.y; acc[6] += v1 * f3.x; acc[7] += v1 * f3.y;
        }
        {
            float2 f0 = __half22float2(*(__half2*)&u2.x), f1 = __half22float2(*(__half2*)&u2.y);
            float2 f2 = __half22float2(*(__half2*)&u2.z), f3 = __half22float2(*(__half2*)&u2.w);
            acc[0] += v2 * f0.x; acc[1] += v2 * f0.y; acc[2] += v2 * f1.x; acc[3] += v2 * f1.y;
            acc[4] += v2 * f2.x; acc[5] += v2 * f2.y; acc[6] += v2 * f3.x; acc[7] += v2 * f3.y;
        }
        {
            float2 f0 = __half22float2(*(__half2*)&u3.x), f1 = __half22float2(*(__half2*)&u3.y);
            float2 f2 = __half22float2(*(__half2*)&u3.z), f3 = __half22float2(*(__half2*)&u3.w);
            acc[0] += v3 * f0.x; acc[1] += v3 * f0.y; acc[2] += v3 * f1.x; acc[3] += v3 * f1.y;
            acc[4] += v3 * f2.x; acc[5] += v3 * f2.y; acc[6] += v3 * f3.x; acc[7] += v3 * f3.y;
        }
    }
    for (; i < e; ++i) {
        int2 p0 = csr[i];
        uint4 u0 = *(const uint4*)(gin + p0.x + koff);
        float v0 = __int_as_float(p0.y);
        float2 f0 = __half22float2(*(__half2*)&u0.x), f1 = __half22float2(*(__half2*)&u0.y);
        float2 f2 = __half22float2(*(__half2*)&u0.z), f3 = __half22float2(*(__half2*)&u0.w);
        acc[0] += v0 * f0.x; acc[1] += v0 * f0.y; acc[2] += v0 * f1.x; acc[3] += v0 * f1.y;
        acc[4] += v0 * f2.x; acc[5] += v0 * f2.y; acc[6] += v0 * f3.x; acc[7] += v0 * f3.y;
    }

    // carry slot: (k-2)&1 == k&1, so read T_{k-2} and write T_k at the SAME
    // address (thread-private location -> safe).
    float* cslot = C32 + ((size_t)(chunk * 2 + (kOut & 1)) * N + n) * BCG + bo;
    float o[8];
#pragma unroll
    for (int q = 0; q < 8; ++q) o[q] = alpha * acc[q];
    if (beta != 0.f) {
        const float4 pv0 = *(const float4*)(cslot);
        const float4 pv1 = *(const float4*)(cslot + 4);
        o[0] += beta * pv0.x; o[1] += beta * pv0.y; o[2] += beta * pv0.z; o[3] += beta * pv0.w;
        o[4] += beta * pv1.x; o[5] += beta * pv1.y; o[6] += beta * pv1.z; o[7] += beta * pv1.w;
    }
    *(float4*)(cslot)     = make_float4(o[0], o[1], o[2], o[3]);
    *(float4*)(cslot + 4) = make_float4(o[4], o[5], o[6], o[7]);
    __half* o16 = X16 + (size_t)(chunk * N + n) * COFF16 + kOut * BCG + bo;
    uint4 h4;
    __half2 h01 = __floats2half2_rn(o[0], o[1]);
    __half2 h23 = __floats2half2_rn(o[2], o[3]);
    __half2 h45 = __floats2half2_rn(o[4], o[5]);
    __half2 h67 = __floats2half2_rn(o[6], o[7]);
    h4.x = *(u32*)&h01; h4.y = *(u32*)&h23; h4.z = *(u32*)&h45; h4.w = *(u32*)&h67;
    *(uint4*)o16 = h4;
}

// ---------------- Fused projection + FC partial ----------------
// Block = 1024 thr = 16 waves; wave = one node x 64 bb lanes. All weight reads
// (WgT row, W_fc row, bias) are wave-uniform -> scalar loads on the SMEM pipe.
// Grid 256*G -> 2 blocks/CU = 32 waves/CU (100% static occupancy; VGPR=24
// leaves registers unconstrained). Zero LDS in hot loop.
// j-loop rolled so LICM can't hoist 200 s_loads (SGPR spill hazard).

__global__ __launch_bounds__(1024, 8)
void proj_fc_kernel(const __half* __restrict__ X16,
                    const float* __restrict__ WgT,    // [j][k] = [10][20]
                    const float* __restrict__ b_gc,
                    const float* __restrict__ W_fc,
                    float* __restrict__ h_part,
                    int N, int b0s, int G) {
    __shared__ float sRed[BCG * 11];
    int tid = threadIdx.x;
    for (int i = tid; i < BCG * 11; i += 1024) sRed[i] = 0.f;
    __syncthreads();

    int g = blockIdx.x % G;
    int bidx = blockIdx.x / G;
    int nblk = gridDim.x / G;

    int bb = tid & (BCG - 1);
    int wv = __builtin_amdgcn_readfirstlane(tid >> 6);   // wave slot 0..15, uniform

    float h_loc[NF];
#pragma unroll
    for (int f = 0; f < NF; ++f) h_loc[f] = 0.f;

    const __half* chunkBase = X16 + (size_t)g * N * COFF16;
    int ngroups = (N + 15) / 16;
    for (int grp = bidx; grp < ngroups; grp += nblk) {
        int n = grp * 16 + wv;                           // uniform per wave
        if (n < N) {
            float xt[KCHEB];
            const __half* xp = chunkBase + (size_t)n * COFF16 + bb;
#pragma unroll
            for (int k = 0; k < KCHEB; ++k) xt[k] = __half2float(xp[k * BCG]);

            const float* wfBase = W_fc + (size_t)n * (NF * NF);
#pragma unroll 1
            for (int j = 0; j < NF; ++j) {
                const float* wg = WgT + j * KCHEB;       // 16B-aligned, contiguous 20f
                float gc = b_gc[j];
#pragma unroll
                for (int k = 0; k < KCHEB; ++k) gc += wg[k] * xt[k];
                gc = fmaxf(gc, 0.f);
                const float* wf = wfBase + j * NF;       // 8B-aligned, contiguous 10f
#pragma unroll
                for (int f = 0; f < NF; ++f) h_loc[f] += gc * wf[f];
            }
        }
    }
#pragma unroll
    for (int f = 0; f < NF; ++f) atomicAdd(&sRed[bb * 11 + f], h_loc[f]);
    __syncthreads();
    for (int i = tid; i < BCG * NF; i += 1024) {
        int rb = i / NF;
        int rf = i - rb * NF;
        atomicAdd(&h_part[(size_t)(b0s + g * BCG + rb) * NF + rf], sRed[rb * 11 + rf]);
    }
}

// ---------------- Bias + ReLU + softmax ----------------

__global__ void softmax_kernel(const float* __restrict__ h_part, const float* __restrict__ b_fc,
                               float* __restrict__ out, int B) {
    int b = blockIdx.x * blockDim.x + threadIdx.x;
    if (b >= B) return;
    float v[NF];
    float m = -1e30f;
#pragma unroll
    for (int f = 0; f < NF; ++f) {
        float t = fmaxf(h_part[b * NF + f] + b_fc[f], 0.f);
        v[f] = t;
        m = fmaxf(m, t);
    }
    float s = 0.f;
#pragma unroll
    for (int f = 0; f < NF; ++f) { v[f] = expf(v[f] - m); s += v[f]; }
    float inv = 1.f / s;
#pragma unroll
    for (int f = 0; f < NF; ++f) out[b * NF + f] = v[f] * inv;
}

// ---------------- launch ----------------

extern "C" void kernel_launch(void* const* d_in, const int* in_sizes, int n_in,
                              void* d_out, int out_size, void* d_ws, size_t ws_size,
                              hipStream_t stream) {
    const float* x    = (const float*)d_in[0];
    const int*   rows = (const int*)d_in[1];
    const int*   cols = (const int*)d_in[2];
    const float* vals = (const float*)d_in[3];
    const float* W_gc = (const float*)d_in[4];
    const float* b_gc = (const float*)d_in[5];
    const float* W_fc = (const float*)d_in[6];
    const float* b_fc = (const float*)d_in[7];
    float* out = (float*)d_out;

    const int E = in_sizes[1];
    const int N = in_sizes[6] / (NF * NF);
    const int B = in_sizes[0] / N;

    // ---- workspace carve ----
    char* p = (char*)d_ws;
    int* counts    = (int*)p;   p += sizeof(int) * (size_t)N;
    int* row_start = (int*)p;   p += sizeof(int) * (size_t)(N + 1);
    int* cursor    = (int*)p;   p += sizeof(int) * (size_t)N;
    int* exbuf     = (int*)p;   p += sizeof(int) * (size_t)N;
    int* bsum      = (int*)p;   p += sizeof(int) * 64;
    int* boff      = (int*)p;   p += sizeof(int) * 64;
    p = (char*)(((size_t)p + 15) & ~(size_t)15);
    int2* csr      = (int2*)p;  p += sizeof(int2) * (size_t)E;
    float* h_part  = (float*)p; p += sizeof(float) * (size_t)B * NF;
    p = (char*)(((size_t)p + 15) & ~(size_t)15);
    float* WgT     = (float*)p; p += sizeof(float) * (size_t)(NF * KCHEB);
    size_t fixed = (size_t)(p - (char*)d_ws);
    fixed = (fixed + 255) & ~(size_t)255;

    // G chunks of BCG=64 resident (G in {2,1}); B=128 -> G=2, single pass
    size_t perChunk16 = (size_t)N * COFF16 * sizeof(__half);     // 51.2 MB
    size_t perCarry   = (size_t)2 * N * BCG * sizeof(float);     // 10.24 MB
    int G = (B >= 2 * BCG) ? 2 : 1;
    while (G > 1 && fixed + (size_t)G * (perChunk16 + perCarry) > ws_size) G >>= 1;
    __half* X16 = (__half*)((char*)d_ws + fixed);
    size_t x16b = ((size_t)G * perChunk16 + 255) & ~(size_t)255;
    float* C32 = (float*)((char*)d_ws + fixed + x16b);
    int xpcShift = (G == 2) ? 2 : 3;
    int BT = G * BCG;
    int nsc = B / BT;

    // ---- CSR build (parallel scan) + WgT prep ----
    {
        int H = B * NF;
        int cov = (N > H) ? N : H;
        int nb = (N + SB - 1) / SB;
        init_kernel<<<(cov + 255) / 256, 256, 0, stream>>>(counts, h_part, W_gc, WgT, N, H);
        hist_kernel<<<(E + 255) / 256, 256, 0, stream>>>(rows, counts, E);
        scan1_kernel<<<nb, SB, 0, stream>>>(counts, exbuf, bsum, N);
        scan2_kernel<<<1, 64, 0, stream>>>(bsum, boff, nb);
        scan3_kernel<<<(N + 256) / 256, 256, 0, stream>>>(row_start, cursor, exbuf, boff, N, nb);
        scatter_kernel<<<(E + 255) / 256, 256, 0, stream>>>(rows, cols, vals, cursor, csr, E);
    }

    int ntiles = (N + 63) / 64;
    int subsPerChunk = (N + 31) / 32;
    int xpc = 1 << xpcShift;
    int gridSpmm = 8 * ((subsPerChunk + xpc - 1) / xpc);

    for (int c = 0; c < nsc; ++c) {
        int b0s = c * BT;
        transpose_kernel<<<G * ntiles, 256, 0, stream>>>(x, X16, C32, N, ntiles, b0s);
        for (int k = 1; k < KCHEB; ++k) {
            float alpha = (k == 1) ? 1.f : 2.f;
            float beta  = (k == 1) ? 0.f : -1.f;
            spmm_kernel<<<gridSpmm, 256, 0, stream>>>(
                X16, C32, row_start, csr, N, xpcShift, subsPerChunk,
                k - 1, k, alpha, beta);
        }
        proj_fc_kernel<<<256 * G, 1024, 0, stream>>>(X16, WgT, b_gc, W_fc, h_part, N, b0s, G);
    }

    softmax_kernel<<<1, 128, 0, stream>>>(h_part, b_fc, out, B);
}